// Round 14
// baseline (253.517 us; speedup 1.0000x reference)
//
#include <hip/hip_runtime.h>

// B=2, S=4096, C=2048, HD=128, H=16
// GEMM: M=8192 (B*S), N=6144 (3*C), K=2048; out = concat(q,k,v) f32 [8192,2048] each.
// R14: independent-barrier-domain experiment. 256-thread blocks (4 waves 1Mx4N),
// tile 128x256, BK=32, per-wave 128x64 (amp unchanged vs R13). LDS 64 KB
// (A 2buf x 8KB, B 3buf x 16KB) -> 2 blocks/CU -> 2 independent barrier domains;
// each SIMD hosts 1 wave of each block (anti-phase overlap, m97/m114 mechanism).
// Single-phase K-tile: stage A(kt+1)+B(kt+2), 12 reads, 32 MFMA, vmcnt(4), 1 barrier.

#define M_DIM 8192
#define N_DIM 6144
#define K_DIM 2048
#define NKT2 64           // K tiles of 32
#define EPS_RMS 1.1920929e-07f

typedef __bf16 bf16x8 __attribute__((ext_vector_type(8)));
typedef float f32x4 __attribute__((ext_vector_type(4)));

__device__ __forceinline__ void gload16(const void* g, void* l) {
  __builtin_amdgcn_global_load_lds(
      (const __attribute__((address_space(1))) unsigned int*)g,
      (__attribute__((address_space(3))) unsigned int*)l, 16, 0, 0);
}

__device__ __forceinline__ unsigned short f2bf(float f) {
  union { float f; unsigned u; } x; x.f = f;
  unsigned r = x.u + 0x7FFFu + ((x.u >> 16) & 1u);   // RNE
  return (unsigned short)(r >> 16);
}

// One launch converts x (16M floats) and wq|wk|wv (3 x 4M floats) to bf16.
__global__ void __launch_bounds__(256) cvt_all(
    const float* __restrict__ x, const float* __restrict__ wq,
    const float* __restrict__ wk, const float* __restrict__ wv,
    unsigned short* __restrict__ xbf, unsigned short* __restrict__ wbf) {
  const int nx4 = M_DIM * K_DIM / 4;
  const int nw4 = K_DIM * K_DIM / 4;
  const int tot = nx4 + 3 * nw4;
  int i = blockIdx.x * blockDim.x + threadIdx.x;
  const int stride = gridDim.x * blockDim.x;
  for (; i < tot; i += stride) {
    const float* s;
    unsigned short* d;
    int j;
    if (i < nx4) { s = x; d = xbf; j = i; }
    else {
      const int k = i - nx4;
      const int sel = k / nw4;
      j = k - sel * nw4;
      s = sel == 0 ? wq : (sel == 1 ? wk : wv);
      d = wbf + (size_t)sel * K_DIM * K_DIM;
    }
    const float4 v = reinterpret_cast<const float4*>(s)[j];
    ushort4 o;
    o.x = f2bf(v.x); o.y = f2bf(v.y); o.z = f2bf(v.z); o.w = f2bf(v.w);
    reinterpret_cast<ushort4*>(d)[j] = o;
  }
}

#define LDS4(ARR, BASE, OFF) (*(const f32x4*)((const char*)(ARR) + (BASE) + (OFF)))
#define FENCE asm volatile("" ::: "memory")

// Tile 128x256, BK=32, 4 waves (1M x 4N), per-wave 128x64, 16x16x32 MFMA.
// LDS layout per operand tile: [rows][4 slots of 16B], slot = chunk ^ ((row>>1)&3)
// (R6-verified 2-way-free pattern). A: 2 buf x 8KB; B: 3 buf x 16KB.
// Ledger per kt: issue [A(kt+1) x2, B(kt+2) x4]; end-of-kt vmcnt(4) drains the
// oldest 6 = B(kt+1)(4) + A(kt+1)(2), leaves B(kt+2) in flight. Never 0 till kt=62.
__global__ void __launch_bounds__(256, 2) gemm_fused(
    const unsigned short* __restrict__ xbf, const unsigned short* __restrict__ wbf,
    const float* __restrict__ rope,
    const float* __restrict__ bq, const float* __restrict__ bk, const float* __restrict__ bv,
    const float* __restrict__ qnw, const float* __restrict__ knw,
    float* __restrict__ dout) {
  const int id = blockIdx.x;
  // XCD-aware, bm-inner: XCD x owns bm in [8x, 8x+8), bm fastest (1536 = 8*192).
  const int xcd = id & 7;
  const int jb = id >> 3;                 // 0..191
  const int bm = (xcd << 3) | (jb & 7);   // 0..63
  const int bn = jb >> 3;                 // 0..23
  const int m0 = bm << 7, n0 = bn << 8;
  const int tid = threadIdx.x;            // 0..255
  const int w = tid >> 6, l = tid & 63;   // w = wave = N-column group 0..3
  const int l15 = l & 15, lhi = l >> 4;

  __shared__ __align__(16) unsigned short As[8192];    // 16 KB = 2 buf x 8 KB
  __shared__ __align__(16) unsigned short Bs[24576];   // 48 KB = 3 buf x 16 KB

  // ---- staging: one gload instr = 256 thr x 16 B = 4 KB = 64 rows x 32 k ----
  // thread t: row_in_unit = w*16 + (l>>2), lds chunk = l&3,
  // global chunk = (l&3) ^ ((row>>1)&3) = (l&3) ^ ((l>>3)&3)   [w*8 = 0 mod 4]
  const int gchunk = (l & 3) ^ ((l >> 3) & 3);
  const unsigned short* aSrc = xbf + ((size_t)(m0 + (w << 4) + (l >> 2)) << 11) + (gchunk << 3);
  const unsigned short* bSrc = wbf + ((size_t)(n0 + (w << 4) + (l >> 2)) << 11) + (gchunk << 3);
  char* aD = (char*)As + (w << 10);
  char* bD = (char*)Bs + (w << 10);

  // A tile = 128 rows = halves H=0,1 ; dest buf (KT&1)*8192
#define STA(KT, H) gload16(aSrc + ((size_t)(H) << 17) + ((KT) << 5), \
                           aD + ((((KT) & 1) << 13) + ((H) << 12)))
  // B tile = 256 rows = quarters Q=0..3 ; dest buf offset BO (0/16384/32768)
#define STB(KT, Q, BO) gload16(bSrc + ((size_t)(Q) << 17) + ((KT) << 5), \
                               bD + ((BO) + ((Q) << 12)))

  // ---- read-side: slot = lhi ^ ((l15>>1)&3); 2-way bank aliasing = free ----
  const int slot = lhi ^ ((l15 >> 1) & 3);
  const unsigned aRdB = (l15 << 6) + (slot << 4);              // + aBuf + mf*1024
  const unsigned bRdB = (w << 12) + (l15 << 6) + (slot << 4);  // + bRB  + nf*1024

  f32x4 acc[8][4];
#pragma unroll
  for (int i = 0; i < 8; ++i)
#pragma unroll
    for (int jj = 0; jj < 4; ++jj) acc[i][jj] = (f32x4){0.f, 0.f, 0.f, 0.f};

  f32x4 Af[8], Bf[4];

  // ---- prologue: [B0(4), A0(2), B1(4)] ; vmcnt(4) drains B0+A0, B1 flies ----
  STB(0, 0, 0); STB(0, 1, 0); STB(0, 2, 0); STB(0, 3, 0);
  STA(0, 0); STA(0, 1);
  STB(1, 0, 16384); STB(1, 1, 16384); STB(1, 2, 16384); STB(1, 3, 16384);
  asm volatile("s_waitcnt vmcnt(4)" ::: "memory");
  __builtin_amdgcn_s_barrier();
  FENCE;

  unsigned aBuf = 0;          // A read buf: kt&1 * 8192
  unsigned bRB = 0;           // B read buf: (kt%3) * 16384
  unsigned bSB = 32768;       // B stage buf: ((kt+2)%3) * 16384
  for (int kt = 0; kt < NKT2; ++kt) {
    // ---- 12 plain reads (compiler-scheduled lgkmcnt vs MFMA) ----
    Af[0] = LDS4(As, aBuf + aRdB, 0);    Af[1] = LDS4(As, aBuf + aRdB, 1024);
    Af[2] = LDS4(As, aBuf + aRdB, 2048); Af[3] = LDS4(As, aBuf + aRdB, 3072);
    Af[4] = LDS4(As, aBuf + aRdB, 4096); Af[5] = LDS4(As, aBuf + aRdB, 5120);
    Af[6] = LDS4(As, aBuf + aRdB, 6144); Af[7] = LDS4(As, aBuf + aRdB, 7168);
    Bf[0] = LDS4(Bs, bRB + bRdB, 0);     Bf[1] = LDS4(Bs, bRB + bRdB, 1024);
    Bf[2] = LDS4(Bs, bRB + bRdB, 2048);  Bf[3] = LDS4(Bs, bRB + bRdB, 3072);
    // ---- stage: A(kt+1) FIRST, then B(kt+2) (issue order = ledger order) ----
    if (kt <= NKT2 - 2) { STA(kt + 1, 0); STA(kt + 1, 1); }
    if (kt <= NKT2 - 3) {
      STB(kt + 2, 0, bSB); STB(kt + 2, 1, bSB);
      STB(kt + 2, 2, bSB); STB(kt + 2, 3, bSB);
    }
    // ---- 32 independent MFMAs ----
    __builtin_amdgcn_s_setprio(1);
#pragma unroll
    for (int mf = 0; mf < 8; ++mf)
#pragma unroll
      for (int nf = 0; nf < 4; ++nf)
        acc[mf][nf] = __builtin_amdgcn_mfma_f32_16x16x32_bf16(
            __builtin_bit_cast(bf16x8, Af[mf]),
            __builtin_bit_cast(bf16x8, Bf[nf]), acc[mf][nf], 0, 0, 0);
    __builtin_amdgcn_s_setprio(0);
    // ---- single boundary sync: counted vmcnt + 1 barrier ----
    if (kt <= NKT2 - 3)      { asm volatile("s_waitcnt vmcnt(4)" ::: "memory"); }
    else if (kt == NKT2 - 2) { asm volatile("s_waitcnt vmcnt(0)" ::: "memory"); }
    __builtin_amdgcn_s_barrier();
    FENCE;
    aBuf ^= 8192u;
    bRB = (bRB == 32768u) ? 0u : bRB + 16384u;
    bSB = (bSB == 32768u) ? 0u : bSB + 16384u;
  }

  // ---- fused epilogue: bias (+ per-head RMSNorm + RoPE for q,k) ----
  float* scr = (float*)As;                       // [4 waves][128 rows] partials
  const int sec = bn >> 3;                       // 0=q 1=k 2=v
  const int nsec = (n0 & 2047) + (w << 6);       // col-in-section base (+nf*16+l15)
  const float* bias = sec == 0 ? bq : (sec == 1 ? bk : bv);
  float biasv[4];
#pragma unroll
  for (int nf = 0; nf < 4; ++nf) biasv[nf] = bias[nsec + nf * 16 + l15];
  const size_t outBase = ((size_t)sec << 24);

  if (sec < 2) {
    const float* nwp = sec ? knw : qnw;
    const int colh = (w & 1) << 6;               // col-in-head base for this wave
    float nwv[4];
#pragma unroll
    for (int nf = 0; nf < 4; ++nf) nwv[nf] = nwp[colh + nf * 16 + l15];
    float ssv[8][4];
#pragma unroll
    for (int mf = 0; mf < 8; ++mf) {
#pragma unroll
      for (int jj = 0; jj < 4; ++jj) {
        float ss = 0.f;
#pragma unroll
        for (int nf = 0; nf < 4; ++nf) {
          const float t = acc[mf][nf][jj] + biasv[nf];
          ss += t * t;
        }
        ss += __shfl_xor(ss, 1);
        ss += __shfl_xor(ss, 2);
        ss += __shfl_xor(ss, 4);
        ss += __shfl_xor(ss, 8);
        ssv[mf][jj] = ss;                        // sum over this wave's 64 cols
      }
    }
    if (l15 == 0) {
#pragma unroll
      for (int mf = 0; mf < 8; ++mf)
#pragma unroll
        for (int jj = 0; jj < 4; ++jj)
          scr[(w << 7) + mf * 16 + (lhi << 2) + jj] = ssv[mf][jj];
    }
    __syncthreads();
#pragma unroll
    for (int mf = 0; mf < 8; ++mf) {
#pragma unroll
      for (int jj = 0; jj < 4; ++jj) {
        const float tot = ssv[mf][jj] + scr[((w ^ 1) << 7) + mf * 16 + (lhi << 2) + jj];
        const float inv = rsqrtf(tot * (1.0f / 128.0f) + EPS_RMS);
        const int m = m0 + mf * 16 + (lhi << 2) + jj;
        const float* rp = rope + ((size_t)(m & 4095) << 8);
        float* orow = dout + outBase + ((size_t)m << 11) + nsec + l15;
#pragma unroll
        for (int nf = 0; nf < 4; ++nf) {
          const float tn = (acc[mf][nf][jj] + biasv[nf]) * inv * nwv[nf];
          const float pn = __shfl_xor(tn, 1);     // partner col^1
          const int ch = colh + nf * 16 + l15;    // col in head
          const int jr = ch >> 1;
          const float o = fmaf(rp[jr << 2], tn, rp[(jr << 2) + 1 + (ch & 1)] * pn);
          orow[nf << 4] = o;
        }
      }
    }
  } else {
#pragma unroll
    for (int mf = 0; mf < 8; ++mf)
#pragma unroll
      for (int jj = 0; jj < 4; ++jj) {
        const int m = m0 + mf * 16 + (lhi << 2) + jj;
        float* orow = dout + outBase + ((size_t)m << 11) + nsec + l15;
#pragma unroll
        for (int nf = 0; nf < 4; ++nf) orow[nf << 4] = acc[mf][nf][jj] + biasv[nf];
      }
  }
}

extern "C" void kernel_launch(void* const* d_in, const int* in_sizes, int n_in,
                              void* d_out, int out_size, void* d_ws, size_t ws_size,
                              hipStream_t stream) {
  const float* x = (const float*)d_in[0];
  const float* rope = (const float*)d_in[1];
  const float* wq = (const float*)d_in[2];
  const float* bq = (const float*)d_in[3];
  const float* wk = (const float*)d_in[4];
  const float* bk = (const float*)d_in[5];
  const float* wv = (const float*)d_in[6];
  const float* bv = (const float*)d_in[7];
  const float* qnw = (const float*)d_in[8];
  const float* knw = (const float*)d_in[9];

  unsigned short* xbf = (unsigned short*)d_ws;                 // 32 MB
  unsigned short* wbf = xbf + (size_t)M_DIM * K_DIM;           // 24 MB

  cvt_all<<<2048, 256, 0, stream>>>(x, wq, wk, wv, xbf, wbf);

  gemm_fused<<<(M_DIM / 128) * (N_DIM / 256), 256, 0, stream>>>(
      xbf, wbf, rope, bq, bk, bv, qnw, knw, (float*)d_out);
}

// Round 15
// 233.541 us; speedup vs baseline: 1.0855x; 1.0855x over previous
//
#include <hip/hip_runtime.h>

// B=2, S=4096, C=2048, HD=128, H=16
// GEMM: M=8192 (B*S), N=6144 (3*C), K=2048; out = concat(q,k,v) f32 [8192,2048] each.
// R15 = R13 (session best: 232.5 us) with s_setprio REMOVED (final T5 ablation;
// m190 evidence: setprio is negative on 2-phase lockstep GEMM structures).
// Everything else identical: 256x256 tile, BK=64, 8 waves, 16x16x32 MFMA,
// both-sides XOR swizzle, 2 phases/kt, counted vmcnt(6)/vmcnt(2), bm-inner
// XCD swizzle, fused single-launch cvt, fused bias+RMSNorm+RoPE epilogue.

#define M_DIM 8192
#define N_DIM 6144
#define K_DIM 2048
#define NKT 32            // K tiles of 64
#define EPS_RMS 1.1920929e-07f

typedef __bf16 bf16x8 __attribute__((ext_vector_type(8)));
typedef float f32x4 __attribute__((ext_vector_type(4)));

__device__ __forceinline__ void gload16(const void* g, void* l) {
  __builtin_amdgcn_global_load_lds(
      (const __attribute__((address_space(1))) unsigned int*)g,
      (__attribute__((address_space(3))) unsigned int*)l, 16, 0, 0);
}

__device__ __forceinline__ unsigned short f2bf(float f) {
  union { float f; unsigned u; } x; x.f = f;
  unsigned r = x.u + 0x7FFFu + ((x.u >> 16) & 1u);   // RNE
  return (unsigned short)(r >> 16);
}

// One launch converts x (16M floats) and wq|wk|wv (3 x 4M floats) to bf16.
__global__ void __launch_bounds__(256) cvt_all(
    const float* __restrict__ x, const float* __restrict__ wq,
    const float* __restrict__ wk, const float* __restrict__ wv,
    unsigned short* __restrict__ xbf, unsigned short* __restrict__ wbf) {
  const int nx4 = M_DIM * K_DIM / 4;
  const int nw4 = K_DIM * K_DIM / 4;
  const int tot = nx4 + 3 * nw4;
  int i = blockIdx.x * blockDim.x + threadIdx.x;
  const int stride = gridDim.x * blockDim.x;
  for (; i < tot; i += stride) {
    const float* s;
    unsigned short* d;
    int j;
    if (i < nx4) { s = x; d = xbf; j = i; }
    else {
      const int k = i - nx4;
      const int sel = k / nw4;
      j = k - sel * nw4;
      s = sel == 0 ? wq : (sel == 1 ? wk : wv);
      d = wbf + (size_t)sel * K_DIM * K_DIM;
    }
    const float4 v = reinterpret_cast<const float4*>(s)[j];
    ushort4 o;
    o.x = f2bf(v.x); o.y = f2bf(v.y); o.z = f2bf(v.z); o.w = f2bf(v.w);
    reinterpret_cast<ushort4*>(d)[j] = o;
  }
}

#define LDS4(ARR, BASE, OFF) (*(const f32x4*)((const char*)(ARR) + (BASE) + (OFF)))

#define MFMA_PH(MH, NH)                                                              \
  {                                                                                  \
    _Pragma("unroll")                                                                \
    for (int mf4 = 0; mf4 < 4; ++mf4) {                                              \
      _Pragma("unroll")                                                              \
      for (int nf2 = 0; nf2 < 2; ++nf2) {                                            \
        f32x4& c = acc[(MH) * 4 + mf4][(NH) * 2 + nf2];                              \
        c = __builtin_amdgcn_mfma_f32_16x16x32_bf16(                                 \
            __builtin_bit_cast(bf16x8, Af[mf4][0]),                                  \
            __builtin_bit_cast(bf16x8, Bf[NH][nf2][0]), c, 0, 0, 0);                 \
        c = __builtin_amdgcn_mfma_f32_16x16x32_bf16(                                 \
            __builtin_bit_cast(bf16x8, Af[mf4][1]),                                  \
            __builtin_bit_cast(bf16x8, Bf[NH][nf2][1]), c, 0, 0, 0);                 \
      }                                                                              \
    }                                                                                \
  }

#define FENCE asm volatile("" ::: "memory")

__global__ void __launch_bounds__(512, 2) gemm_fused(
    const unsigned short* __restrict__ xbf, const unsigned short* __restrict__ wbf,
    const float* __restrict__ rope,
    const float* __restrict__ bq, const float* __restrict__ bk, const float* __restrict__ bv,
    const float* __restrict__ qnw, const float* __restrict__ knw,
    float* __restrict__ dout) {
  const int id = blockIdx.x;
  // XCD-aware, bm-inner: XCD x owns bm in [4x,4x+4), bm fastest -> small L2 set.
  const int xcd = id & 7;
  const int jb = id >> 3;                // 0..95
  const int bm = (xcd << 2) | (jb & 3);  // 0..31
  const int bn = jb >> 2;                // 0..23
  const int m0 = bm << 8, n0 = bn << 8;
  const int tid = threadIdx.x;
  const int w = tid >> 6, l = tid & 63;
  const int l15 = l & 15, lhi = l >> 4;
  const int wr = w >> 2, wc = w & 3;

  __shared__ __align__(16) unsigned short As[32768];   // 64 KB
  __shared__ __align__(16) unsigned short Bs[32768];   // 64 KB

  // ---- staging (linear LDS dest, inverse-swizzled global source) ----
  const int srow = tid >> 3;                       // 0..63 within a quarter
  const int schunk = (tid & 7) ^ (srow & 7);       // involution
  const unsigned short* aSrc = xbf + ((size_t)(m0 + srow) << 11) + (schunk << 3);
  const unsigned short* bSrc = wbf + ((size_t)(n0 + srow) << 11) + (schunk << 3);
  char* aDst = (char*)As + (w << 10);
  char* bDst = (char*)Bs + (w << 10);

#define STA(KT, Q) gload16(aSrc + ((size_t)(Q) << 17) + ((KT) << 6), aDst + ((((KT) & 1) << 15) + ((Q) << 13)))
#define STB(KT, Q) gload16(bSrc + ((size_t)(Q) << 17) + ((KT) << 6), bDst + ((((KT) & 1) << 15) + ((Q) << 13)))

  // ---- read-side swizzled byte offsets (k-slot XOR row&7) ----
  const int sl0 = ((lhi ^ (l15 & 7)) << 4);        // k-slots 0..3  (k 0..31)
  const int sl1 = (((lhi + 4) ^ (l15 & 7)) << 4);  // k-slots 4..7  (k 32..63)
  unsigned a0 = (wr << 14) + (l15 << 7) + sl0;
  unsigned a1 = (wr << 14) + (l15 << 7) + sl1;
  unsigned b0 = (wc << 13) + (l15 << 7) + sl0;
  unsigned b1 = (wc << 13) + (l15 << 7) + sl1;

  f32x4 acc[8][4];
#pragma unroll
  for (int i = 0; i < 8; ++i)
#pragma unroll
    for (int jj = 0; jj < 4; ++jj) acc[i][jj] = (f32x4){0.f, 0.f, 0.f, 0.f};

  f32x4 Af[4][2];        // current A-half fragments (k-slices 0/1)
  f32x4 Bf[2][2][2];     // both B col-halves, held across the K-tile

  // ---- prologue: kt0's 6 ph0-needed loads, then its 2 A q1/q3 ----
  STA(0, 0); STA(0, 2);
  STB(0, 0); STB(0, 1); STB(0, 2); STB(0, 3);
  STA(0, 1); STA(0, 3);
  asm volatile("s_waitcnt vmcnt(2)" ::: "memory");
  __builtin_amdgcn_s_barrier();
  FENCE;

  for (int kt = 0; kt < NKT; ++kt) {
    const bool notLast = (kt < NKT - 1);
    // ================ phase 0 : A-h0 + B(all), MFMA Q00,Q01 ================
    Af[0][0] = LDS4(As, a0, 0);        Af[0][1] = LDS4(As, a1, 0);
    Bf[0][0][0] = LDS4(Bs, b0, 0);     Bf[0][0][1] = LDS4(Bs, b1, 0);
    Bf[0][1][0] = LDS4(Bs, b0, 2048);  Bf[0][1][1] = LDS4(Bs, b1, 2048);
    Af[1][0] = LDS4(As, a0, 2048);     Af[1][1] = LDS4(As, a1, 2048);
    Af[2][0] = LDS4(As, a0, 4096);     Af[2][1] = LDS4(As, a1, 4096);
    Af[3][0] = LDS4(As, a0, 6144);     Af[3][1] = LDS4(As, a1, 6144);
    Bf[1][0][0] = LDS4(Bs, b0, 4096);  Bf[1][0][1] = LDS4(Bs, b1, 4096);
    Bf[1][1][0] = LDS4(Bs, b0, 6144);  Bf[1][1][1] = LDS4(Bs, b1, 6144);
    if (notLast) {
      STA(kt + 1, 0); STA(kt + 1, 2);
      STB(kt + 1, 0); STB(kt + 1, 1); STB(kt + 1, 2); STB(kt + 1, 3);
    }
    MFMA_PH(0, 0);
    MFMA_PH(0, 1);
    if (notLast) { asm volatile("s_waitcnt vmcnt(6)" ::: "memory"); }
    else         { asm volatile("s_waitcnt vmcnt(0)" ::: "memory"); }
    __builtin_amdgcn_s_barrier();
    FENCE;
    // ================ phase 1 : A-h1, MFMA Q10,Q11 (B in regs) ================
    Af[0][0] = LDS4(As, a0, 8192);  Af[0][1] = LDS4(As, a1, 8192);
    Af[1][0] = LDS4(As, a0, 10240); Af[1][1] = LDS4(As, a1, 10240);
    Af[2][0] = LDS4(As, a0, 12288); Af[2][1] = LDS4(As, a1, 12288);
    Af[3][0] = LDS4(As, a0, 14336); Af[3][1] = LDS4(As, a1, 14336);
    if (notLast) { STA(kt + 1, 1); STA(kt + 1, 3); }
    MFMA_PH(1, 0);
    MFMA_PH(1, 1);
    if (notLast) { asm volatile("s_waitcnt vmcnt(2)" ::: "memory"); }
    __builtin_amdgcn_s_barrier();
    FENCE;
    a0 ^= 32768u; a1 ^= 32768u; b0 ^= 32768u; b1 ^= 32768u;
  }

  // ---- fused epilogue: bias (+ per-head RMSNorm + RoPE for q,k) ----
  float* scr = (float*)As;                       // [8 waves][128 rows] partials
  const int sec = bn >> 3;                       // 0=q 1=k 2=v
  const int nsec = (n0 & 2047) + (wc << 6);      // col-in-section base (+nf*16+l15)
  const float* bias = sec == 0 ? bq : (sec == 1 ? bk : bv);
  float biasv[4];
#pragma unroll
  for (int nf = 0; nf < 4; ++nf) biasv[nf] = bias[nsec + nf * 16 + l15];
  const size_t outBase = ((size_t)sec << 24);

  if (sec < 2) {
    const float* nwp = sec ? knw : qnw;
    const int colh = (wc & 1) << 6;              // col-in-head base for this wave
    float nwv[4];
#pragma unroll
    for (int nf = 0; nf < 4; ++nf) nwv[nf] = nwp[colh + nf * 16 + l15];
    float ssv[8][4];
#pragma unroll
    for (int mf = 0; mf < 8; ++mf) {
#pragma unroll
      for (int jj = 0; jj < 4; ++jj) {
        float ss = 0.f;
#pragma unroll
        for (int nf = 0; nf < 4; ++nf) {
          const float t = acc[mf][nf][jj] + biasv[nf];
          ss += t * t;
        }
        ss += __shfl_xor(ss, 1);
        ss += __shfl_xor(ss, 2);
        ss += __shfl_xor(ss, 4);
        ss += __shfl_xor(ss, 8);
        ssv[mf][jj] = ss;                        // sum over this wave's 64 cols
      }
    }
    if (l15 == 0) {
#pragma unroll
      for (int mf = 0; mf < 8; ++mf)
#pragma unroll
        for (int jj = 0; jj < 4; ++jj)
          scr[(w << 7) + mf * 16 + (lhi << 2) + jj] = ssv[mf][jj];
    }
    __syncthreads();
#pragma unroll
    for (int mf = 0; mf < 8; ++mf) {
#pragma unroll
      for (int jj = 0; jj < 4; ++jj) {
        const float tot = ssv[mf][jj] + scr[((w ^ 1) << 7) + mf * 16 + (lhi << 2) + jj];
        const float inv = rsqrtf(tot * (1.0f / 128.0f) + EPS_RMS);
        const int m = m0 + (wr << 7) + mf * 16 + (lhi << 2) + jj;
        const float* rp = rope + ((size_t)(m & 4095) << 8);
        float* orow = dout + outBase + ((size_t)m << 11) + nsec + l15;
#pragma unroll
        for (int nf = 0; nf < 4; ++nf) {
          const float tn = (acc[mf][nf][jj] + biasv[nf]) * inv * nwv[nf];
          const float pn = __shfl_xor(tn, 1);     // partner col^1
          const int ch = colh + nf * 16 + l15;    // col in head
          const int jr = ch >> 1;
          const float o = fmaf(rp[jr << 2], tn, rp[(jr << 2) + 1 + (ch & 1)] * pn);
          orow[nf << 4] = o;
        }
      }
    }
  } else {
#pragma unroll
    for (int mf = 0; mf < 8; ++mf)
#pragma unroll
      for (int jj = 0; jj < 4; ++jj) {
        const int m = m0 + (wr << 7) + mf * 16 + (lhi << 2) + jj;
        float* orow = dout + outBase + ((size_t)m << 11) + nsec + l15;
#pragma unroll
        for (int nf = 0; nf < 4; ++nf) orow[nf << 4] = acc[mf][nf][jj] + biasv[nf];
      }
  }
}

extern "C" void kernel_launch(void* const* d_in, const int* in_sizes, int n_in,
                              void* d_out, int out_size, void* d_ws, size_t ws_size,
                              hipStream_t stream) {
  const float* x = (const float*)d_in[0];
  const float* rope = (const float*)d_in[1];
  const float* wq = (const float*)d_in[2];
  const float* bq = (const float*)d_in[3];
  const float* wk = (const float*)d_in[4];
  const float* bk = (const float*)d_in[5];
  const float* wv = (const float*)d_in[6];
  const float* bv = (const float*)d_in[7];
  const float* qnw = (const float*)d_in[8];
  const float* knw = (const float*)d_in[9];

  unsigned short* xbf = (unsigned short*)d_ws;                 // 32 MB
  unsigned short* wbf = xbf + (size_t)M_DIM * K_DIM;           // 24 MB

  cvt_all<<<2048, 256, 0, stream>>>(x, wq, wk, wv, xbf, wbf);

  gemm_fused<<<(M_DIM / 256) * (N_DIM / 256), 512, 0, stream>>>(
      xbf, wbf, rope, bq, bk, bv, qnw, knw, (float*)d_out);
}